// Round 5
// baseline (628.074 us; speedup 1.0000x reference)
//
#include <hip/hip_runtime.h>
#include <hip/hip_bf16.h>
#include <math.h>

// ---------- constants ----------
#define B_ 8
#define N_ 1025
#define C_ 768
#define NH_ 12
#define HID_ 3072
#define M_ 8200            // B_*N_
#define SCALE_ 0.125f

typedef __bf16 bf16x8 __attribute__((ext_vector_type(8)));
typedef float f32x4 __attribute__((ext_vector_type(4)));
typedef unsigned short u16x8 __attribute__((ext_vector_type(8)));

__device__ __forceinline__ float b2f(unsigned short u) {
  unsigned int v = ((unsigned int)u) << 16;
  return __builtin_bit_cast(float, v);
}
__device__ __forceinline__ unsigned short f2b(float f) {
  unsigned int x = __builtin_bit_cast(unsigned int, f);
  unsigned int r = (x + 0x7fffu + ((x >> 16) & 1u)) >> 16;
  return (unsigned short)r;
}
__device__ __forceinline__ void gll16(const void* g, void* l) {
  __builtin_amdgcn_global_load_lds(
      (const __attribute__((address_space(1))) unsigned int*)g,
      (__attribute__((address_space(3))) unsigned int*)l, 16, 0, 0);
}

// ---------- bf16 GEMM, BK=64, LDS double-buffered pipeline (T3 min-2-phase) ----------
// C(MxN) = A(MxK) * BT(NxK)^T + bias (+EPI) (+resid). resid/Cout may alias.
// Per K-step: STAGE(next buf) issued FIRST, then ds_read+MFMA on cur buf, then ONE
// barrier (its implicit vmcnt(0)/lgkmcnt(0) drain lands after compute -> latency hidden).
template<int EPI, typename OutT>
__global__ __launch_bounds__(256, 2)
void gemm_bt(const unsigned short* __restrict__ A, const unsigned short* __restrict__ BT,
             const float* __restrict__ bias, const float* resid,
             OutT* Cout, int M, int N, int K)
{
  __shared__ __align__(16) unsigned short As[2][128 * 64];
  __shared__ __align__(16) unsigned short Bs[2][128 * 64];
  const int nTn = N >> 7;
  const int bi = blockIdx.x / nTn, bj = blockIdx.x % nTn;
  const int tid = threadIdx.x, lane = tid & 63, wid = tid >> 6;
  const int wr = (wid >> 1) << 6, wc = (wid & 1) << 6;
  const int row0 = bi << 7, col0 = bj << 7;

  f32x4 acc[4][4];
  #pragma unroll
  for (int m = 0; m < 4; ++m)
    #pragma unroll
    for (int n = 0; n < 4; ++n) acc[m][n] = (f32x4){0.f, 0.f, 0.f, 0.f};

  const int fr = lane & 15;
  const int fk4 = lane >> 4;          // 16B-chunk index within a 32-k half

  // staging: 1024 16B-chunks per matrix; lds dest linear (wave-uniform base + lane*16),
  // global source pre-swizzled (rule #21 both-sides)
  auto stage = [&](int buf, int k0) {
    #pragma unroll
    for (int e = 0; e < 4; ++e) {
      int idx = e * 256 + tid;          // 16B chunk 0..1023
      int r = idx >> 3, s = idx & 7;    // row, lds slot
      int ch = ((s ^ (r & 7)) << 3);    // swizzled element offset in row
      int gra = row0 + r; gra = gra < M ? gra : M - 1;
      gll16(A + (size_t)gra * K + k0 + ch, &As[buf][(size_t)(e * 256 + wid * 64) * 8]);
      gll16(BT + (size_t)(col0 + r) * K + k0 + ch, &Bs[buf][(size_t)(e * 256 + wid * 64) * 8]);
    }
  };

  const int T = K >> 6;
  int cur = 0;
  stage(0, 0);
  __syncthreads();

  for (int t = 0; t < T; ++t) {
    if (t + 1 < T) stage(cur ^ 1, (t + 1) << 6);   // prefetch next tile (in flight during MFMA)
    #pragma unroll
    for (int kk = 0; kk < 2; ++kk) {
      bf16x8 af[4], bfr[4];
      #pragma unroll
      for (int m = 0; m < 4; ++m) {
        int row = wr + m * 16 + fr;
        int slot = (kk * 4 + fk4) ^ (row & 7);
        af[m] = *(const bf16x8*)(&As[cur][row * 64 + slot * 8]);
      }
      #pragma unroll
      for (int n = 0; n < 4; ++n) {
        int row = wc + n * 16 + fr;
        int slot = (kk * 4 + fk4) ^ (row & 7);
        bfr[n] = *(const bf16x8*)(&Bs[cur][row * 64 + slot * 8]);
      }
      #pragma unroll
      for (int m = 0; m < 4; ++m)
        #pragma unroll
        for (int n = 0; n < 4; ++n)
          acc[m][n] = __builtin_amdgcn_mfma_f32_16x16x32_bf16(af[m], bfr[n], acc[m][n], 0, 0, 0);
    }
    __syncthreads();   // drains this wave's prefetch vmcnt + protects LDS reuse
    cur ^= 1;
  }

  const int fq = (lane >> 4) << 2;
  #pragma unroll
  for (int n = 0; n < 4; ++n) {
    int gcol = col0 + wc + n * 16 + fr;
    float bv = bias ? bias[gcol] : 0.f;
    #pragma unroll
    for (int m = 0; m < 4; ++m) {
      int grb = row0 + wr + m * 16 + fq;
      #pragma unroll
      for (int j = 0; j < 4; ++j) {
        int gr = grb + j;
        if (gr < M) {
          float v = acc[m][n][j] + bv;
          if (EPI == 1) v = 0.5f * v * (1.f + erff(v * 0.70710678118654752f));
          if (resid) v += resid[(size_t)gr * N + gcol];
          if constexpr (sizeof(OutT) == 2) Cout[(size_t)gr * N + gcol] = (OutT)f2b(v);
          else                              Cout[(size_t)gr * N + gcol] = v;
        }
      }
    }
  }
}

// ---------- transpose + f32->bf16 ----------
__global__ __launch_bounds__(256)
void transpose_kernel(const float* __restrict__ in, unsigned short* __restrict__ out,
                      int R, int Ccols)
{
  __shared__ float t[32][33];
  int bx = blockIdx.x << 5, by = blockIdx.y << 5;
  int tx = threadIdx.x & 31, ty = threadIdx.x >> 5;
  #pragma unroll
  for (int j = ty; j < 32; j += 8)
    t[j][tx] = in[(size_t)(by + j) * Ccols + bx + tx];
  __syncthreads();
  #pragma unroll
  for (int j = ty; j < 32; j += 8)
    out[(size_t)(bx + j) * R + by + tx] = f2b(t[tx][j]);
}

// ---------- cls rows of x1 ----------
__global__ __launch_bounds__(256)
void cls_copy(const float* __restrict__ x, float* __restrict__ x1)
{
  int b = blockIdx.x;
  for (int c = threadIdx.x; c < C_; c += 256)
    x1[(size_t)b * N_ * C_ + c] = x[(size_t)b * N_ * C_ + c];
}

// ---------- CPE 3x3 dwconv, LDS-tiled: x1 = dwconv(feat)+bias+feat ----------
__global__ __launch_bounds__(256, 2)
void cpe_tile(const float* __restrict__ x, const float* __restrict__ cw,
              const float* __restrict__ cb, float* __restrict__ x1)
{
  __shared__ __align__(16) float xt[6 * 34 * 36];   // ch padded 32->36 (144B rows)
  __shared__ __align__(16) float wsm[9][32];
  __shared__ float bsm[32];
  int b = blockIdx.x, hb = blockIdx.y, cc = blockIdx.z;
  int c0 = cc * 32;
  int tid = threadIdx.x;
  for (int i = tid; i < 9 * 32; i += 256) wsm[i >> 5][i & 31] = cw[(i >> 5) * C_ + c0 + (i & 31)];
  if (tid < 32) bsm[tid] = cb[c0 + tid];
  for (int i = tid; i < 6 * 34 * 8; i += 256) {
    int g = i & 7, rw = i >> 3, w = rw % 34, r = rw / 34;
    int hh = hb * 4 - 1 + r, ww = w - 1;
    f32x4 val = (f32x4){0.f, 0.f, 0.f, 0.f};
    if (hh >= 0 && hh < 32 && ww >= 0 && ww < 32)
      val = *(const f32x4*)(x + (size_t)(b * N_ + 1 + hh * 32 + ww) * C_ + c0 + g * 4);
    *(f32x4*)&xt[(r * 34 + w) * 36 + g * 4] = val;
  }
  __syncthreads();
  int w = tid >> 3, cg = tid & 7;
  #pragma unroll
  for (int h = 0; h < 4; ++h) {
    f32x4 acc = *(const f32x4*)&bsm[cg * 4];
    #pragma unroll
    for (int kh = 0; kh < 3; ++kh)
      #pragma unroll
      for (int kw = 0; kw < 3; ++kw) {
        f32x4 v = *(const f32x4*)&xt[((h + kh) * 34 + (w + kw)) * 36 + cg * 4];
        f32x4 wv = *(const f32x4*)&wsm[kh * 3 + kw][cg * 4];
        acc += v * wv;
      }
    acc += *(const f32x4*)&xt[((h + 1) * 34 + (w + 1)) * 36 + cg * 4];  // residual center
    int n = 1 + (hb * 4 + h) * 32 + w;
    *(f32x4*)&x1[(size_t)(b * N_ + n) * C_ + c0 + cg * 4] = acc;
  }
}

// ---------- LayerNorm: f32 in -> bf16 out ----------
__global__ __launch_bounds__(256)
void ln_kernel(const float* __restrict__ xin, const float* __restrict__ g,
               const float* __restrict__ bt, unsigned short* __restrict__ outp)
{
  int row = blockIdx.x;
  int tid = threadIdx.x;
  const float* xr = xin + (size_t)row * C_;
  float v0 = xr[tid], v1 = xr[tid + 256], v2 = xr[tid + 512];
  float s = v0 + v1 + v2;
  float ss = v0 * v0 + v1 * v1 + v2 * v2;
  #pragma unroll
  for (int off = 32; off >= 1; off >>= 1) {
    s += __shfl_down(s, off);
    ss += __shfl_down(ss, off);
  }
  __shared__ float sm[4], sm2[4];
  if ((tid & 63) == 0) { sm[tid >> 6] = s; sm2[tid >> 6] = ss; }
  __syncthreads();
  s = sm[0] + sm[1] + sm[2] + sm[3];
  ss = sm2[0] + sm2[1] + sm2[2] + sm2[3];
  float mean = s * (1.f / C_);
  float var = ss * (1.f / C_) - mean * mean;
  float inv = rsqrtf(var + 1e-6f);
  unsigned short* orow = outp + (size_t)row * C_;
  orow[tid]       = f2b((v0 - mean) * inv * g[tid]       + bt[tid]);
  orow[tid + 256] = f2b((v1 - mean) * inv * g[tid + 256] + bt[tid + 256]);
  orow[tid + 512] = f2b((v2 - mean) * inv * g[tid + 512] + bt[tid + 512]);
}

// ---------- k-softmax stats, partial over token-residues ----------
__global__ __launch_bounds__(256)
void ksoft_part(const unsigned short* __restrict__ qkv, float* __restrict__ pmax,
                float* __restrict__ psum)
{
  int bh = blockIdx.x, part = blockIdx.y;   // (96,16)
  int b = bh / NH_, h = bh % NH_;
  int tid = threadIdx.x, c = tid & 63, sub = tid >> 6;
  float m = -1e30f, s = 0.f;
  for (int n = part * 4 + sub; n < N_; n += 64) {
    float v = b2f(qkv[(size_t)(b * N_ + n) * 2304 + 768 + h * 64 + c]);
    if (v > m) { s = s * expf(m - v) + 1.f; m = v; }
    else       { s += expf(v - m); }
  }
  __shared__ float ms[4][64], ss[4][64];
  ms[sub][c] = m; ss[sub][c] = s;
  __syncthreads();
  if (sub == 0) {
    float M = ms[0][c];
    #pragma unroll
    for (int p = 1; p < 4; ++p) M = fmaxf(M, ms[p][c]);
    float S = 0.f;
    #pragma unroll
    for (int p = 0; p < 4; ++p) S += ss[p][c] * expf(ms[p][c] - M);
    pmax[((size_t)bh * 16 + part) * 64 + c] = M;
    psum[((size_t)bh * 16 + part) * 64 + c] = S;
  }
}

__global__ __launch_bounds__(256)
void ksoft_comb(const float* __restrict__ pmax, const float* __restrict__ psum,
                float* __restrict__ colmax, float* __restrict__ colsum)
{
  int gid = blockIdx.x * 256 + threadIdx.x;   // 24 blocks -> 6144 = 96*64
  int bh = gid >> 6, c = gid & 63;
  float M = -1e30f;
  for (int p = 0; p < 16; ++p) M = fmaxf(M, pmax[((size_t)bh * 16 + p) * 64 + c]);
  float S = 0.f;
  for (int p = 0; p < 16; ++p)
    S += psum[((size_t)bh * 16 + p) * 64 + c] * expf(pmax[((size_t)bh * 16 + p) * 64 + c] - M);
  colmax[bh * 64 + c] = M;
  colsum[bh * 64 + c] = S;
}

// ---------- fa partial: fa[c][d] += ksm[n,c]*v[n,d] over a token range ----------
__global__ __launch_bounds__(256)
void fa_part(const unsigned short* __restrict__ qkv, const float* __restrict__ colmax,
             const float* __restrict__ colsum, unsigned short* __restrict__ fap)
{
  int bh = blockIdx.x, part = blockIdx.y;   // (96,16)
  int b = bh / NH_, h = bh % NH_;
  int tid = threadIdx.x;
  int n_lo = part * 65, n_hi = n_lo + 65; if (n_hi > N_) n_hi = N_;
  __shared__ float ks[8][64], vs[8][64];
  __shared__ float cm[64], cs[64];
  if (tid < 64) { cm[tid] = colmax[bh * 64 + tid]; cs[tid] = 1.f / colsum[bh * 64 + tid]; }
  __syncthreads();
  f32x4 acc4[4];
  #pragma unroll
  for (int j = 0; j < 4; ++j) acc4[j] = (f32x4){0.f, 0.f, 0.f, 0.f};
  int c = tid >> 2, dg = (tid & 3) << 4;
  for (int n0 = n_lo; n0 < n_hi; n0 += 8) {
    int nr = n_hi - n0; nr = nr < 8 ? nr : 8;
    for (int idx = tid; idx < nr * 64; idx += 256) {
      int r = idx >> 6, cc = idx & 63;
      size_t ro = (size_t)(b * N_ + n0 + r) * 2304;
      ks[r][cc] = expf(b2f(qkv[ro + 768 + h * 64 + cc]) - cm[cc]) * cs[cc];
      vs[r][cc] = b2f(qkv[ro + 1536 + h * 64 + cc]);
    }
    __syncthreads();
    for (int r = 0; r < nr; ++r) {
      float kk = ks[r][c];
      #pragma unroll
      for (int j4 = 0; j4 < 4; ++j4)
        acc4[j4] += kk * *(const f32x4*)&vs[r][dg + j4 * 4];
    }
    __syncthreads();
  }
  #pragma unroll
  for (int j4 = 0; j4 < 4; ++j4)
    #pragma unroll
    for (int j = 0; j < 4; ++j)
      fap[((size_t)bh * 16 + part) * 4096 + c * 64 + dg + j4 * 4 + j] = f2b(acc4[j4][j]);
}

// ---------- combine fa partials, write TRANSPOSED fa_t[d][c] ----------
__global__ __launch_bounds__(256)
void fa_comb(const unsigned short* __restrict__ fap, float* __restrict__ fat)
{
  int bh = blockIdx.x;          // 96
  int tid = threadIdx.x;
  int c = tid >> 2, d0 = (tid & 3) * 16;
  #pragma unroll
  for (int j = 0; j < 16; ++j) {
    float s = 0.f;
    for (int p = 0; p < 16; ++p)
      s += b2f(fap[((size_t)bh * 16 + p) * 4096 + c * 64 + d0 + j]);
    fat[(size_t)bh * 4096 + (d0 + j) * 64 + c] = s;
  }
}

// ---------- CRPE dwconv, LDS-tiled, templated kernel size ----------
template<int KSZ>
__global__ __launch_bounds__(256, 2)
void cv_tile(const unsigned short* __restrict__ qkv, const float* __restrict__ wgt,
             const float* __restrict__ bias, int cbase, unsigned short* __restrict__ cv)
{
  constexpr int PAD = KSZ / 2;
  constexpr int HT = 3 + KSZ;
  constexpr int WT = 31 + KSZ;
  __shared__ __align__(16) unsigned short vt[HT * WT * 72];  // ch padded 64->72 (144B rows)
  __shared__ __align__(16) unsigned short wsm[KSZ * KSZ * 64];
  __shared__ float bsm[64];
  int b = blockIdx.x, hb = blockIdx.y, cc = blockIdx.z;
  int c0 = cbase + cc * 64, co0 = cc * 64;
  int tid = threadIdx.x;
  for (int i = tid; i < KSZ * KSZ * 64; i += 256)
    wsm[i] = f2b(wgt[(i >> 6) * 256 + co0 + (i & 63)]);
  if (tid < 64) bsm[tid] = bias[co0 + tid];
  for (int i = tid; i < HT * WT * 8; i += 256) {
    int g = i & 7, rw = i >> 3, w = rw % WT, r = rw / WT;
    int hh = hb * 4 - PAD + r, ww = w - PAD;
    bf16x8 val;
    #pragma unroll
    for (int z = 0; z < 8; ++z) val[z] = (__bf16)0.0f;
    if (hh >= 0 && hh < 32 && ww >= 0 && ww < 32)
      val = *(const bf16x8*)(qkv + (size_t)(b * N_ + 1 + hh * 32 + ww) * 2304 + 1536 + c0 + g * 8);
    *(bf16x8*)&vt[(r * WT + w) * 72 + g * 8] = val;
  }
  __syncthreads();
  int w = tid >> 3, cg = tid & 7;
  #pragma unroll
  for (int h = 0; h < 4; ++h) {
    float acc[8];
    #pragma unroll
    for (int j = 0; j < 8; ++j) acc[j] = bsm[cg * 8 + j];
    #pragma unroll
    for (int kh = 0; kh < KSZ; ++kh)
      #pragma unroll
      for (int kw = 0; kw < KSZ; ++kw) {
        bf16x8 v = *(const bf16x8*)&vt[((h + kh) * WT + (w + kw)) * 72 + cg * 8];
        bf16x8 wv = *(const bf16x8*)&wsm[(kh * KSZ + kw) * 64 + cg * 8];
        #pragma unroll
        for (int j = 0; j < 8; ++j)
          acc[j] += (float)v[j] * (float)wv[j];
      }
    int hw = (hb * 4 + h) * 32 + w;
    u16x8 res;
    #pragma unroll
    for (int j = 0; j < 8; ++j) res[j] = f2b(acc[j]);
    *(u16x8*)&cv[((size_t)b * 1024 + hw) * C_ + c0 + cg * 8] = res;
  }
}

// ---------- att: out = SCALE * q@fa + q*cv(shifted) ; wave-per-token ----------
__global__ __launch_bounds__(256)
void att_wave(const unsigned short* __restrict__ qkv, const float* __restrict__ fat,
              const unsigned short* __restrict__ cv, unsigned short* __restrict__ outp)
{
  int bh = blockIdx.x, chunk = blockIdx.y;   // (96,16)
  int b = bh / NH_, h = bh % NH_;
  int tid = threadIdx.x, lane = tid & 63, wid = tid >> 6;
  __shared__ __align__(16) float fas[64 * 68];   // [d][c], padded 64->68
  for (int i = tid; i < 4096; i += 256)
    fas[(i >> 6) * 68 + (i & 63)] = fat[(size_t)bh * 4096 + i];
  __syncthreads();
  for (int n = chunk * 4 + wid; n < N_; n += 64) {
    const unsigned short* qrow = qkv + (size_t)(b * N_ + n) * 2304 + h * 64;
    float a = 0.f;
    #pragma unroll
    for (int c8 = 0; c8 < 8; ++c8) {
      bf16x8 qv = *(const bf16x8*)(qrow + c8 * 8);
      f32x4 f0 = *(const f32x4*)&fas[lane * 68 + c8 * 8];
      f32x4 f1 = *(const f32x4*)&fas[lane * 68 + c8 * 8 + 4];
      a += (float)qv[0] * f0[0] + (float)qv[1] * f0[1] + (float)qv[2] * f0[2] + (float)qv[3] * f0[3]
         + (float)qv[4] * f1[0] + (float)qv[5] * f1[1] + (float)qv[6] * f1[2] + (float)qv[7] * f1[3];
    }
    float val = SCALE_ * a;
    if (n >= 1) {
      float qd = b2f(qrow[lane]);
      val += qd * b2f(cv[(size_t)(b * 1024 + n - 1) * C_ + h * 64 + lane]);
    }
    outp[(size_t)(b * N_ + n) * C_ + h * 64 + lane] = f2b(val);
  }
}

// ---------- launch ----------
extern "C" void kernel_launch(void* const* d_in, const int* in_sizes, int n_in,
                              void* d_out, int out_size, void* d_ws, size_t ws_size,
                              hipStream_t stream)
{
  const float* x     = (const float*)d_in[0];
  const float* cpe_w = (const float*)d_in[3];
  const float* cpe_b = (const float*)d_in[4];
  const float* g1    = (const float*)d_in[5];
  const float* bta1  = (const float*)d_in[6];
  const float* qkv_w = (const float*)d_in[7];
  const float* qkv_b = (const float*)d_in[8];
  const float* w3    = (const float*)d_in[9];
  const float* b3    = (const float*)d_in[10];
  const float* w5    = (const float*)d_in[11];
  const float* b5    = (const float*)d_in[12];
  const float* w7    = (const float*)d_in[13];
  const float* b7    = (const float*)d_in[14];
  const float* proj_w= (const float*)d_in[15];
  const float* proj_b= (const float*)d_in[16];
  const float* g2    = (const float*)d_in[17];
  const float* bta2  = (const float*)d_in[18];
  const float* mw1   = (const float*)d_in[19];
  const float* mb1   = (const float*)d_in[20];
  const float* mw2   = (const float*)d_in[21];
  const float* mb2   = (const float*)d_in[22];

  char* ws = (char*)d_ws;
  size_t o = 0;
  auto alloc = [&](size_t bytes) { size_t r = o; o += (bytes + 255) & ~(size_t)255; return r; };
  size_t off_qkvT  = alloc(768UL * 2304 * 2);
  size_t off_projT = alloc(768UL * 768 * 2);
  size_t off_w1T   = alloc(768UL * 3072 * 2);
  size_t off_w2T   = alloc(3072UL * 768 * 2);
  size_t off_act   = alloc((size_t)M_ * C_ * 2);
  size_t off_x1    = alloc((size_t)M_ * C_ * 4);        // x1, then x2 in-place
  size_t off_qkv   = alloc((size_t)M_ * 2304 * 2);      // hid alias starts here
  size_t off_pmax  = alloc(96UL * 16 * 64 * 4);
  size_t off_psum  = alloc(96UL * 16 * 64 * 4);
  size_t off_cmax  = alloc(96UL * 64 * 4);
  size_t off_csum  = alloc(96UL * 64 * 4);
  size_t off_fat   = alloc(96UL * 4096 * 4);
  size_t off_tmp12 = alloc(96UL * 16 * 4096 * 2);       // fa partials, then cv (both 12.58MB)
  size_t needed = o;

  if (ws_size < needed) {   // diagnostic fallback -> absmax reads ~5.9
    hipMemsetAsync(d_out, 0, (size_t)out_size * 4, stream);
    return;
  }

  unsigned short* qkvT  = (unsigned short*)(ws + off_qkvT);
  unsigned short* projT = (unsigned short*)(ws + off_projT);
  unsigned short* w1T   = (unsigned short*)(ws + off_w1T);
  unsigned short* w2T   = (unsigned short*)(ws + off_w2T);
  unsigned short* act   = (unsigned short*)(ws + off_act);
  float*          x1    = (float*)(ws + off_x1);
  unsigned short* qkvb  = (unsigned short*)(ws + off_qkv);
  float*          pmax  = (float*)(ws + off_pmax);
  float*          psum  = (float*)(ws + off_psum);
  float*          cmax  = (float*)(ws + off_cmax);
  float*          csum  = (float*)(ws + off_csum);
  float*          fat   = (float*)(ws + off_fat);
  unsigned short* tmp12 = (unsigned short*)(ws + off_tmp12);
  unsigned short* hid   = qkvb;   // 50.4MB alias over dead qkv..tmp12 (52.8MB)

  dim3 blk(256);
  transpose_kernel<<<dim3(2304 / 32, 768 / 32), blk, 0, stream>>>(qkv_w, qkvT, 768, 2304);
  transpose_kernel<<<dim3(768 / 32, 768 / 32), blk, 0, stream>>>(proj_w, projT, 768, 768);
  transpose_kernel<<<dim3(3072 / 32, 768 / 32), blk, 0, stream>>>(mw1, w1T, 768, 3072);
  transpose_kernel<<<dim3(768 / 32, 3072 / 32), blk, 0, stream>>>(mw2, w2T, 3072, 768);
  cls_copy<<<8, blk, 0, stream>>>(x, x1);
  cpe_tile<<<dim3(8, 8, 24), blk, 0, stream>>>(x, cpe_w, cpe_b, x1);
  ln_kernel<<<M_, blk, 0, stream>>>(x1, g1, bta1, act);
  gemm_bt<0, unsigned short><<<65 * 18, blk, 0, stream>>>(act, qkvT, qkv_b, nullptr, qkvb, M_, 2304, 768);
  ksoft_part<<<dim3(96, 16), blk, 0, stream>>>(qkvb, pmax, psum);
  ksoft_comb<<<24, blk, 0, stream>>>(pmax, psum, cmax, csum);
  fa_part<<<dim3(96, 16), blk, 0, stream>>>(qkvb, cmax, csum, tmp12);
  fa_comb<<<96, blk, 0, stream>>>(tmp12, fat);
  cv_tile<3><<<dim3(8, 8, 4), blk, 0, stream>>>(qkvb, w3, b3, 0, tmp12);
  cv_tile<5><<<dim3(8, 8, 4), blk, 0, stream>>>(qkvb, w5, b5, 256, tmp12);
  cv_tile<7><<<dim3(8, 8, 4), blk, 0, stream>>>(qkvb, w7, b7, 512, tmp12);
  att_wave<<<dim3(96, 16), blk, 0, stream>>>(qkvb, fat, tmp12, act);
  gemm_bt<0, float><<<65 * 6, blk, 0, stream>>>(act, projT, proj_b, x1, x1, M_, 768, 768);
  ln_kernel<<<M_, blk, 0, stream>>>(x1, g2, bta2, act);
  gemm_bt<1, unsigned short><<<65 * 24, blk, 0, stream>>>(act, w1T, mb1, nullptr, hid, M_, HID_, 768);
  gemm_bt<0, float><<<65 * 6, blk, 0, stream>>>(hid, w2T, mb2, x1, (float*)d_out, M_, 768, HID_);
}

// Round 6
// 573.372 us; speedup vs baseline: 1.0954x; 1.0954x over previous
//
#include <hip/hip_runtime.h>
#include <hip/hip_bf16.h>
#include <math.h>

// ---------- constants ----------
#define B_ 8
#define N_ 1025
#define C_ 768
#define NH_ 12
#define HID_ 3072
#define M_ 8200            // B_*N_
#define SCALE_ 0.125f

typedef __bf16 bf16x8 __attribute__((ext_vector_type(8)));
typedef float f32x4 __attribute__((ext_vector_type(4)));
typedef unsigned short u16x8 __attribute__((ext_vector_type(8)));

__device__ __forceinline__ float b2f(unsigned short u) {
  unsigned int v = ((unsigned int)u) << 16;
  return __builtin_bit_cast(float, v);
}
__device__ __forceinline__ unsigned short f2b(float f) {
  unsigned int x = __builtin_bit_cast(unsigned int, f);
  unsigned int r = (x + 0x7fffu + ((x >> 16) & 1u)) >> 16;
  return (unsigned short)r;
}
__device__ __forceinline__ void gll16(const void* g, void* l) {
  __builtin_amdgcn_global_load_lds(
      (const __attribute__((address_space(1))) unsigned int*)g,
      (__attribute__((address_space(3))) unsigned int*)l, 16, 0, 0);
}

// ---------- bf16 GEMM, BK=64, single-buffer (round-4 structure) + XCD swizzle ----------
// C(MxN) = A(MxK) * BT(NxK)^T + bias (+EPI) (+resid). resid/Cout may alias.
// EPI: 0 none, 1 tanh-GELU (max err vs exact erf-GELU ~3e-4).
template<int EPI, typename OutT>
__global__ __launch_bounds__(256, 2)
void gemm_bt(const unsigned short* __restrict__ A, const unsigned short* __restrict__ BT,
             const float* __restrict__ bias, const float* resid,
             OutT* Cout, int M, int N, int K)
{
  __shared__ __align__(16) unsigned short As[128 * 64];
  __shared__ __align__(16) unsigned short Bs[128 * 64];
  const int nTn = N >> 7;
  // T1 bijective XCD swizzle (m204): contiguous tile chunk per XCD -> A-panel L2 reuse
  const int nwg = gridDim.x, bid = blockIdx.x;
  const int q = nwg >> 3, r8 = nwg & 7;
  const int xcd = bid & 7, lid = bid >> 3;
  const int tile = (xcd < r8 ? xcd * (q + 1) : r8 * (q + 1) + (xcd - r8) * q) + lid;
  const int bi = tile / nTn, bj = tile % nTn;
  const int tid = threadIdx.x, lane = tid & 63, wid = tid >> 6;
  const int wr = (wid >> 1) << 6, wc = (wid & 1) << 6;
  const int row0 = bi << 7, col0 = bj << 7;

  f32x4 acc[4][4];
  #pragma unroll
  for (int m = 0; m < 4; ++m)
    #pragma unroll
    for (int n = 0; n < 4; ++n) acc[m][n] = (f32x4){0.f, 0.f, 0.f, 0.f};

  const int fr = lane & 15;
  const int fk4 = lane >> 4;          // 16B-chunk index within a 32-k half

  for (int k0 = 0; k0 < K; k0 += 64) {
    // stage 128x64 A and BT tiles; LDS linear dest, global chunk pre-swizzled (rule #21)
    #pragma unroll
    for (int e = 0; e < 4; ++e) {
      int idx = e * 256 + tid;          // 16B chunk 0..1023
      int rr = idx >> 3, s = idx & 7;   // row, lds slot
      int ch = ((s ^ (rr & 7)) << 3);   // swizzled element offset in row
      int gra = row0 + rr; gra = gra < M ? gra : M - 1;
      gll16(A + (size_t)gra * K + k0 + ch, As + (size_t)(e * 256 + wid * 64) * 8);
      gll16(BT + (size_t)(col0 + rr) * K + k0 + ch, Bs + (size_t)(e * 256 + wid * 64) * 8);
    }
    __syncthreads();
    #pragma unroll
    for (int kk = 0; kk < 2; ++kk) {
      bf16x8 af[4], bfr[4];
      #pragma unroll
      for (int m = 0; m < 4; ++m) {
        int row = wr + m * 16 + fr;
        int slot = (kk * 4 + fk4) ^ (row & 7);
        af[m] = *(const bf16x8*)(As + row * 64 + slot * 8);
      }
      #pragma unroll
      for (int n = 0; n < 4; ++n) {
        int row = wc + n * 16 + fr;
        int slot = (kk * 4 + fk4) ^ (row & 7);
        bfr[n] = *(const bf16x8*)(Bs + row * 64 + slot * 8);
      }
      #pragma unroll
      for (int m = 0; m < 4; ++m)
        #pragma unroll
        for (int n = 0; n < 4; ++n)
          acc[m][n] = __builtin_amdgcn_mfma_f32_16x16x32_bf16(af[m], bfr[n], acc[m][n], 0, 0, 0);
    }
    __syncthreads();
  }

  const int fq = (lane >> 4) << 2;
  #pragma unroll
  for (int n = 0; n < 4; ++n) {
    int gcol = col0 + wc + n * 16 + fr;
    float bv = bias ? bias[gcol] : 0.f;
    #pragma unroll
    for (int m = 0; m < 4; ++m) {
      int grb = row0 + wr + m * 16 + fq;
      #pragma unroll
      for (int j = 0; j < 4; ++j) {
        int gr = grb + j;
        if (gr < M) {
          float v = acc[m][n][j] + bv;
          if (EPI == 1) {
            // tanh-form GELU: 0.5v(1+tanh(0.79788(v+0.044715v^3))); tanh via hw exp2/rcp
            float u = v * (0.7978845608f + 0.0447149984f * v * v);
            float e = __builtin_amdgcn_exp2f(u * 2.8853900818f);   // e^{2u}
            float th = 1.f - 2.f * __builtin_amdgcn_rcpf(e + 1.f);
            v = 0.5f * v * (1.f + th);
          }
          if (resid) v += resid[(size_t)gr * N + gcol];
          if constexpr (sizeof(OutT) == 2) Cout[(size_t)gr * N + gcol] = (OutT)f2b(v);
          else                              Cout[(size_t)gr * N + gcol] = v;
        }
      }
    }
  }
}

// ---------- transpose + f32->bf16 ----------
__global__ __launch_bounds__(256)
void transpose_kernel(const float* __restrict__ in, unsigned short* __restrict__ out,
                      int R, int Ccols)
{
  __shared__ float t[32][33];
  int bx = blockIdx.x << 5, by = blockIdx.y << 5;
  int tx = threadIdx.x & 31, ty = threadIdx.x >> 5;
  #pragma unroll
  for (int j = ty; j < 32; j += 8)
    t[j][tx] = in[(size_t)(by + j) * Ccols + bx + tx];
  __syncthreads();
  #pragma unroll
  for (int j = ty; j < 32; j += 8)
    out[(size_t)(bx + j) * R + by + tx] = f2b(t[tx][j]);
}

// ---------- cls rows of x1 ----------
__global__ __launch_bounds__(256)
void cls_copy(const float* __restrict__ x, float* __restrict__ x1)
{
  int b = blockIdx.x;
  for (int c = threadIdx.x; c < C_; c += 256)
    x1[(size_t)b * N_ * C_ + c] = x[(size_t)b * N_ * C_ + c];
}

// ---------- CPE 3x3 dwconv, LDS-tiled: x1 = dwconv(feat)+bias+feat ----------
__global__ __launch_bounds__(256, 2)
void cpe_tile(const float* __restrict__ x, const float* __restrict__ cw,
              const float* __restrict__ cb, float* __restrict__ x1)
{
  __shared__ __align__(16) float xt[6 * 34 * 36];   // ch padded 32->36 (144B rows)
  __shared__ __align__(16) float wsm[9][32];
  __shared__ float bsm[32];
  int b = blockIdx.x, hb = blockIdx.y, cc = blockIdx.z;
  int c0 = cc * 32;
  int tid = threadIdx.x;
  for (int i = tid; i < 9 * 32; i += 256) wsm[i >> 5][i & 31] = cw[(i >> 5) * C_ + c0 + (i & 31)];
  if (tid < 32) bsm[tid] = cb[c0 + tid];
  for (int i = tid; i < 6 * 34 * 8; i += 256) {
    int g = i & 7, rw = i >> 3, w = rw % 34, r = rw / 34;
    int hh = hb * 4 - 1 + r, ww = w - 1;
    f32x4 val = (f32x4){0.f, 0.f, 0.f, 0.f};
    if (hh >= 0 && hh < 32 && ww >= 0 && ww < 32)
      val = *(const f32x4*)(x + (size_t)(b * N_ + 1 + hh * 32 + ww) * C_ + c0 + g * 4);
    *(f32x4*)&xt[(r * 34 + w) * 36 + g * 4] = val;
  }
  __syncthreads();
  int w = tid >> 3, cg = tid & 7;
  #pragma unroll
  for (int h = 0; h < 4; ++h) {
    f32x4 acc = *(const f32x4*)&bsm[cg * 4];
    #pragma unroll
    for (int kh = 0; kh < 3; ++kh)
      #pragma unroll
      for (int kw = 0; kw < 3; ++kw) {
        f32x4 v = *(const f32x4*)&xt[((h + kh) * 34 + (w + kw)) * 36 + cg * 4];
        f32x4 wv = *(const f32x4*)&wsm[kh * 3 + kw][cg * 4];
        acc += v * wv;
      }
    acc += *(const f32x4*)&xt[((h + 1) * 34 + (w + 1)) * 36 + cg * 4];  // residual center
    int n = 1 + (hb * 4 + h) * 32 + w;
    *(f32x4*)&x1[(size_t)(b * N_ + n) * C_ + c0 + cg * 4] = acc;
  }
}

// ---------- LayerNorm: f32 in -> bf16 out ----------
__global__ __launch_bounds__(256)
void ln_kernel(const float* __restrict__ xin, const float* __restrict__ g,
               const float* __restrict__ bt, unsigned short* __restrict__ outp)
{
  int row = blockIdx.x;
  int tid = threadIdx.x;
  const float* xr = xin + (size_t)row * C_;
  float v0 = xr[tid], v1 = xr[tid + 256], v2 = xr[tid + 512];
  float s = v0 + v1 + v2;
  float ss = v0 * v0 + v1 * v1 + v2 * v2;
  #pragma unroll
  for (int off = 32; off >= 1; off >>= 1) {
    s += __shfl_down(s, off);
    ss += __shfl_down(ss, off);
  }
  __shared__ float sm[4], sm2[4];
  if ((tid & 63) == 0) { sm[tid >> 6] = s; sm2[tid >> 6] = ss; }
  __syncthreads();
  s = sm[0] + sm[1] + sm[2] + sm[3];
  ss = sm2[0] + sm2[1] + sm2[2] + sm2[3];
  float mean = s * (1.f / C_);
  float var = ss * (1.f / C_) - mean * mean;
  float inv = rsqrtf(var + 1e-6f);
  unsigned short* orow = outp + (size_t)row * C_;
  orow[tid]       = f2b((v0 - mean) * inv * g[tid]       + bt[tid]);
  orow[tid + 256] = f2b((v1 - mean) * inv * g[tid + 256] + bt[tid + 256]);
  orow[tid + 512] = f2b((v2 - mean) * inv * g[tid + 512] + bt[tid + 512]);
}

// ---------- k-softmax stats, partial over token-residues ----------
__global__ __launch_bounds__(256)
void ksoft_part(const unsigned short* __restrict__ qkv, float* __restrict__ pmax,
                float* __restrict__ psum)
{
  int bh = blockIdx.x, part = blockIdx.y;   // (96,16)
  int b = bh / NH_, h = bh % NH_;
  int tid = threadIdx.x, c = tid & 63, sub = tid >> 6;
  float m = -1e30f, s = 0.f;
  for (int n = part * 4 + sub; n < N_; n += 64) {
    float v = b2f(qkv[(size_t)(b * N_ + n) * 2304 + 768 + h * 64 + c]);
    if (v > m) { s = s * expf(m - v) + 1.f; m = v; }
    else       { s += expf(v - m); }
  }
  __shared__ float ms[4][64], ss[4][64];
  ms[sub][c] = m; ss[sub][c] = s;
  __syncthreads();
  if (sub == 0) {
    float M = ms[0][c];
    #pragma unroll
    for (int p = 1; p < 4; ++p) M = fmaxf(M, ms[p][c]);
    float S = 0.f;
    #pragma unroll
    for (int p = 0; p < 4; ++p) S += ss[p][c] * expf(ms[p][c] - M);
    pmax[((size_t)bh * 16 + part) * 64 + c] = M;
    psum[((size_t)bh * 16 + part) * 64 + c] = S;
  }
}

__global__ __launch_bounds__(256)
void ksoft_comb(const float* __restrict__ pmax, const float* __restrict__ psum,
                float* __restrict__ colmax, float* __restrict__ colsum)
{
  int gid = blockIdx.x * 256 + threadIdx.x;   // 24 blocks -> 6144 = 96*64
  int bh = gid >> 6, c = gid & 63;
  float M = -1e30f;
  for (int p = 0; p < 16; ++p) M = fmaxf(M, pmax[((size_t)bh * 16 + p) * 64 + c]);
  float S = 0.f;
  for (int p = 0; p < 16; ++p)
    S += psum[((size_t)bh * 16 + p) * 64 + c] * expf(pmax[((size_t)bh * 16 + p) * 64 + c] - M);
  colmax[bh * 64 + c] = M;
  colsum[bh * 64 + c] = S;
}

// ---------- fa partial: fa[c][d] += ksm[n,c]*v[n,d] over a token range ----------
__global__ __launch_bounds__(256)
void fa_part(const unsigned short* __restrict__ qkv, const float* __restrict__ colmax,
             const float* __restrict__ colsum, unsigned short* __restrict__ fap)
{
  int bh = blockIdx.x, part = blockIdx.y;   // (96,16)
  int b = bh / NH_, h = bh % NH_;
  int tid = threadIdx.x;
  int n_lo = part * 65, n_hi = n_lo + 65; if (n_hi > N_) n_hi = N_;
  __shared__ float ks[8][64], vs[8][64];
  __shared__ float cm[64], cs[64];
  if (tid < 64) { cm[tid] = colmax[bh * 64 + tid]; cs[tid] = 1.f / colsum[bh * 64 + tid]; }
  __syncthreads();
  f32x4 acc4[4];
  #pragma unroll
  for (int j = 0; j < 4; ++j) acc4[j] = (f32x4){0.f, 0.f, 0.f, 0.f};
  int c = tid >> 2, dg = (tid & 3) << 4;
  for (int n0 = n_lo; n0 < n_hi; n0 += 8) {
    int nr = n_hi - n0; nr = nr < 8 ? nr : 8;
    for (int idx = tid; idx < nr * 64; idx += 256) {
      int r = idx >> 6, cc = idx & 63;
      size_t ro = (size_t)(b * N_ + n0 + r) * 2304;
      ks[r][cc] = expf(b2f(qkv[ro + 768 + h * 64 + cc]) - cm[cc]) * cs[cc];
      vs[r][cc] = b2f(qkv[ro + 1536 + h * 64 + cc]);
    }
    __syncthreads();
    for (int r = 0; r < nr; ++r) {
      float kk = ks[r][c];
      #pragma unroll
      for (int j4 = 0; j4 < 4; ++j4)
        acc4[j4] += kk * *(const f32x4*)&vs[r][dg + j4 * 4];
    }
    __syncthreads();
  }
  #pragma unroll
  for (int j4 = 0; j4 < 4; ++j4)
    #pragma unroll
    for (int j = 0; j < 4; ++j)
      fap[((size_t)bh * 16 + part) * 4096 + c * 64 + dg + j4 * 4 + j] = f2b(acc4[j4][j]);
}

// ---------- combine fa partials, write TRANSPOSED fa_t[d][c] ----------
__global__ __launch_bounds__(256)
void fa_comb(const unsigned short* __restrict__ fap, float* __restrict__ fat)
{
  int bh = blockIdx.x;          // 96
  int tid = threadIdx.x;
  int c = tid >> 2, d0 = (tid & 3) * 16;
  #pragma unroll
  for (int j = 0; j < 16; ++j) {
    float s = 0.f;
    for (int p = 0; p < 16; ++p)
      s += b2f(fap[((size_t)bh * 16 + p) * 4096 + c * 64 + d0 + j]);
    fat[(size_t)bh * 4096 + (d0 + j) * 64 + c] = s;
  }
}

// ---------- CRPE dwconv, LDS-tiled, templated kernel size ----------
template<int KSZ>
__global__ __launch_bounds__(256, 2)
void cv_tile(const unsigned short* __restrict__ qkv, const float* __restrict__ wgt,
             const float* __restrict__ bias, int cbase, unsigned short* __restrict__ cv)
{
  constexpr int PAD = KSZ / 2;
  constexpr int HT = 3 + KSZ;
  constexpr int WT = 31 + KSZ;
  __shared__ __align__(16) unsigned short vt[HT * WT * 72];  // ch padded 64->72 (144B rows)
  __shared__ __align__(16) unsigned short wsm[KSZ * KSZ * 64];
  __shared__ float bsm[64];
  int b = blockIdx.x, hb = blockIdx.y, cc = blockIdx.z;
  int c0 = cbase + cc * 64, co0 = cc * 64;
  int tid = threadIdx.x;
  for (int i = tid; i < KSZ * KSZ * 64; i += 256)
    wsm[i] = f2b(wgt[(i >> 6) * 256 + co0 + (i & 63)]);
  if (tid < 64) bsm[tid] = bias[co0 + tid];
  for (int i = tid; i < HT * WT * 8; i += 256) {
    int g = i & 7, rw = i >> 3, w = rw % WT, r = rw / WT;
    int hh = hb * 4 - PAD + r, ww = w - PAD;
    bf16x8 val;
    #pragma unroll
    for (int z = 0; z < 8; ++z) val[z] = (__bf16)0.0f;
    if (hh >= 0 && hh < 32 && ww >= 0 && ww < 32)
      val = *(const bf16x8*)(qkv + (size_t)(b * N_ + 1 + hh * 32 + ww) * 2304 + 1536 + c0 + g * 8);
    *(bf16x8*)&vt[(r * WT + w) * 72 + g * 8] = val;
  }
  __syncthreads();
  int w = tid >> 3, cg = tid & 7;
  #pragma unroll
  for (int h = 0; h < 4; ++h) {
    float acc[8];
    #pragma unroll
    for (int j = 0; j < 8; ++j) acc[j] = bsm[cg * 8 + j];
    #pragma unroll
    for (int kh = 0; kh < KSZ; ++kh)
      #pragma unroll
      for (int kw = 0; kw < KSZ; ++kw) {
        bf16x8 v = *(const bf16x8*)&vt[((h + kh) * WT + (w + kw)) * 72 + cg * 8];
        bf16x8 wv = *(const bf16x8*)&wsm[(kh * KSZ + kw) * 64 + cg * 8];
        #pragma unroll
        for (int j = 0; j < 8; ++j)
          acc[j] += (float)v[j] * (float)wv[j];
      }
    int hw = (hb * 4 + h) * 32 + w;
    u16x8 res;
    #pragma unroll
    for (int j = 0; j < 8; ++j) res[j] = f2b(acc[j]);
    *(u16x8*)&cv[((size_t)b * 1024 + hw) * C_ + c0 + cg * 8] = res;
  }
}

// ---------- att: out = SCALE * q@fa + q*cv(shifted) ; wave-per-token ----------
__global__ __launch_bounds__(256)
void att_wave(const unsigned short* __restrict__ qkv, const float* __restrict__ fat,
              const unsigned short* __restrict__ cv, unsigned short* __restrict__ outp)
{
  int bh = blockIdx.x, chunk = blockIdx.y;   // (96,16)
  int b = bh / NH_, h = bh % NH_;
  int tid = threadIdx.x, lane = tid & 63, wid = tid >> 6;
  __shared__ __align__(16) float fas[64 * 68];   // [d][c], padded 64->68
  for (int i = tid; i < 4096; i += 256)
    fas[(i >> 6) * 68 + (i & 63)] = fat[(size_t)bh * 4096 + i];
  __syncthreads();
  for (int n = chunk * 4 + wid; n < N_; n += 64) {
    const unsigned short* qrow = qkv + (size_t)(b * N_ + n) * 2304 + h * 64;
    float a = 0.f;
    #pragma unroll
    for (int c8 = 0; c8 < 8; ++c8) {
      bf16x8 qv = *(const bf16x8*)(qrow + c8 * 8);
      f32x4 f0 = *(const f32x4*)&fas[lane * 68 + c8 * 8];
      f32x4 f1 = *(const f32x4*)&fas[lane * 68 + c8 * 8 + 4];
      a += (float)qv[0] * f0[0] + (float)qv[1] * f0[1] + (float)qv[2] * f0[2] + (float)qv[3] * f0[3]
         + (float)qv[4] * f1[0] + (float)qv[5] * f1[1] + (float)qv[6] * f1[2] + (float)qv[7] * f1[3];
    }
    float val = SCALE_ * a;
    if (n >= 1) {
      float qd = b2f(qrow[lane]);
      val += qd * b2f(cv[(size_t)(b * 1024 + n - 1) * C_ + h * 64 + lane]);
    }
    outp[(size_t)(b * N_ + n) * C_ + h * 64 + lane] = f2b(val);
  }
}

// ---------- launch ----------
extern "C" void kernel_launch(void* const* d_in, const int* in_sizes, int n_in,
                              void* d_out, int out_size, void* d_ws, size_t ws_size,
                              hipStream_t stream)
{
  const float* x     = (const float*)d_in[0];
  const float* cpe_w = (const float*)d_in[3];
  const float* cpe_b = (const float*)d_in[4];
  const float* g1    = (const float*)d_in[5];
  const float* bta1  = (const float*)d_in[6];
  const float* qkv_w = (const float*)d_in[7];
  const float* qkv_b = (const float*)d_in[8];
  const float* w3    = (const float*)d_in[9];
  const float* b3    = (const float*)d_in[10];
  const float* w5    = (const float*)d_in[11];
  const float* b5    = (const float*)d_in[12];
  const float* w7    = (const float*)d_in[13];
  const float* b7    = (const float*)d_in[14];
  const float* proj_w= (const float*)d_in[15];
  const float* proj_b= (const float*)d_in[16];
  const float* g2    = (const float*)d_in[17];
  const float* bta2  = (const float*)d_in[18];
  const float* mw1   = (const float*)d_in[19];
  const float* mb1   = (const float*)d_in[20];
  const float* mw2   = (const float*)d_in[21];
  const float* mb2   = (const float*)d_in[22];

  char* ws = (char*)d_ws;
  size_t o = 0;
  auto alloc = [&](size_t bytes) { size_t r = o; o += (bytes + 255) & ~(size_t)255; return r; };
  size_t off_qkvT  = alloc(768UL * 2304 * 2);
  size_t off_projT = alloc(768UL * 768 * 2);
  size_t off_w1T   = alloc(768UL * 3072 * 2);
  size_t off_w2T   = alloc(3072UL * 768 * 2);
  size_t off_act   = alloc((size_t)M_ * C_ * 2);
  size_t off_x1    = alloc((size_t)M_ * C_ * 4);        // x1, then x2 in-place
  size_t off_qkv   = alloc((size_t)M_ * 2304 * 2);      // hid alias starts here
  size_t off_pmax  = alloc(96UL * 16 * 64 * 4);
  size_t off_psum  = alloc(96UL * 16 * 64 * 4);
  size_t off_cmax  = alloc(96UL * 64 * 4);
  size_t off_csum  = alloc(96UL * 64 * 4);
  size_t off_fat   = alloc(96UL * 4096 * 4);
  size_t off_tmp12 = alloc(96UL * 16 * 4096 * 2);       // fa partials, then cv (both 12.58MB)
  size_t needed = o;

  if (ws_size < needed) {   // diagnostic fallback -> absmax reads ~5.9
    hipMemsetAsync(d_out, 0, (size_t)out_size * 4, stream);
    return;
  }

  unsigned short* qkvT  = (unsigned short*)(ws + off_qkvT);
  unsigned short* projT = (unsigned short*)(ws + off_projT);
  unsigned short* w1T   = (unsigned short*)(ws + off_w1T);
  unsigned short* w2T   = (unsigned short*)(ws + off_w2T);
  unsigned short* act   = (unsigned short*)(ws + off_act);
  float*          x1    = (float*)(ws + off_x1);
  unsigned short* qkvb  = (unsigned short*)(ws + off_qkv);
  float*          pmax  = (float*)(ws + off_pmax);
  float*          psum  = (float*)(ws + off_psum);
  float*          cmax  = (float*)(ws + off_cmax);
  float*          csum  = (float*)(ws + off_csum);
  float*          fat   = (float*)(ws + off_fat);
  unsigned short* tmp12 = (unsigned short*)(ws + off_tmp12);
  unsigned short* hid   = qkvb;   // 50.4MB alias over dead qkv..tmp12 (52.8MB)

  dim3 blk(256);
  transpose_kernel<<<dim3(2304 / 32, 768 / 32), blk, 0, stream>>>(qkv_w, qkvT, 768, 2304);
  transpose_kernel<<<dim3(768 / 32, 768 / 32), blk, 0, stream>>>(proj_w, projT, 768, 768);
  transpose_kernel<<<dim3(3072 / 32, 768 / 32), blk, 0, stream>>>(mw1, w1T, 768, 3072);
  transpose_kernel<<<dim3(768 / 32, 3072 / 32), blk, 0, stream>>>(mw2, w2T, 3072, 768);
  cls_copy<<<8, blk, 0, stream>>>(x, x1);
  cpe_tile<<<dim3(8, 8, 24), blk, 0, stream>>>(x, cpe_w, cpe_b, x1);
  ln_kernel<<<M_, blk, 0, stream>>>(x1, g1, bta1, act);
  gemm_bt<0, unsigned short><<<65 * 18, blk, 0, stream>>>(act, qkvT, qkv_b, nullptr, qkvb, M_, 2304, 768);
  ksoft_part<<<dim3(96, 16), blk, 0, stream>>>(qkvb, pmax, psum);
  ksoft_comb<<<24, blk, 0, stream>>>(pmax, psum, cmax, csum);
  fa_part<<<dim3(96, 16), blk, 0, stream>>>(qkvb, cmax, csum, tmp12);
  fa_comb<<<96, blk, 0, stream>>>(tmp12, fat);
  cv_tile<3><<<dim3(8, 8, 4), blk, 0, stream>>>(qkvb, w3, b3, 0, tmp12);
  cv_tile<5><<<dim3(8, 8, 4), blk, 0, stream>>>(qkvb, w5, b5, 256, tmp12);
  cv_tile<7><<<dim3(8, 8, 4), blk, 0, stream>>>(qkvb, w7, b7, 512, tmp12);
  att_wave<<<dim3(96, 16), blk, 0, stream>>>(qkvb, fat, tmp12, act);
  gemm_bt<0, float><<<65 * 6, blk, 0, stream>>>(act, projT, proj_b, x1, x1, M_, 768, 768);
  ln_kernel<<<M_, blk, 0, stream>>>(x1, g2, bta2, act);
  gemm_bt<1, unsigned short><<<65 * 24, blk, 0, stream>>>(act, w1T, mb1, nullptr, hid, M_, HID_, 768);
  gemm_bt<0, float><<<65 * 6, blk, 0, stream>>>(hid, w2T, mb2, x1, (float*)d_out, M_, 768, HID_);
}

// Round 7
// 518.973 us; speedup vs baseline: 1.2102x; 1.1048x over previous
//
#include <hip/hip_runtime.h>
#include <hip/hip_bf16.h>
#include <math.h>

// ---------- constants ----------
#define B_ 8
#define N_ 1025
#define C_ 768
#define NH_ 12
#define HID_ 3072
#define M_ 8200            // B_*N_
#define SCALE_ 0.125f
#define LOG2E_ 1.4426950408889634f

typedef __bf16 bf16x8 __attribute__((ext_vector_type(8)));
typedef float f32x4 __attribute__((ext_vector_type(4)));
typedef unsigned short u16x8 __attribute__((ext_vector_type(8)));

__device__ __forceinline__ float b2f(unsigned short u) {
  unsigned int v = ((unsigned int)u) << 16;
  return __builtin_bit_cast(float, v);
}
__device__ __forceinline__ unsigned short f2b(float f) {
  unsigned int x = __builtin_bit_cast(unsigned int, f);
  unsigned int r = (x + 0x7fffu + ((x >> 16) & 1u)) >> 16;
  return (unsigned short)r;
}
__device__ __forceinline__ void gll16(const void* g, void* l) {
  __builtin_amdgcn_global_load_lds(
      (const __attribute__((address_space(1))) unsigned int*)g,
      (__attribute__((address_space(3))) unsigned int*)l, 16, 0, 0);
}

// ---------- bf16 GEMM, BK=64, single-buffer + XCD swizzle + LDS-transposed epilogue ----
// C(MxN) = A(MxK) * BT(NxK)^T + bias (+EPI) (+resid). resid/Cout may alias elementwise.
// EPI: 0 none, 1 tanh-GELU.
template<int EPI, typename OutT>
__global__ __launch_bounds__(256, 2)
void gemm_bt(const unsigned short* __restrict__ A, const unsigned short* __restrict__ BT,
             const float* __restrict__ bias, const float* resid,
             OutT* Cout, int M, int N, int K)
{
  // union: staging (2 x 128x64 bf16 = 32KB)  |  epilogue ctT[128 cols][68] f32 = 34.8KB
  __shared__ __align__(16) char smem[34816];
  unsigned short* As = (unsigned short*)smem;
  unsigned short* Bs = As + 128 * 64;
  float* ctT = (float*)smem;

  const int nTn = N >> 7;
  // T1 bijective XCD swizzle (m204)
  const int nwg = gridDim.x, bid = blockIdx.x;
  const int q = nwg >> 3, r8 = nwg & 7;
  const int xcd = bid & 7, lid = bid >> 3;
  const int tile = (xcd < r8 ? xcd * (q + 1) : r8 * (q + 1) + (xcd - r8) * q) + lid;
  const int bi = tile / nTn, bj = tile % nTn;
  const int tid = threadIdx.x, lane = tid & 63, wid = tid >> 6;
  const int wr = (wid >> 1) << 6, wc = (wid & 1) << 6;
  const int row0 = bi << 7, col0 = bj << 7;

  f32x4 acc[4][4];
  #pragma unroll
  for (int m = 0; m < 4; ++m)
    #pragma unroll
    for (int n = 0; n < 4; ++n) acc[m][n] = (f32x4){0.f, 0.f, 0.f, 0.f};

  const int fr = lane & 15;
  const int fk4 = lane >> 4;

  for (int k0 = 0; k0 < K; k0 += 64) {
    #pragma unroll
    for (int e = 0; e < 4; ++e) {
      int idx = e * 256 + tid;          // 16B chunk 0..1023
      int rr = idx >> 3, s = idx & 7;
      int ch = ((s ^ (rr & 7)) << 3);   // pre-swizzled source (rule #21)
      int gra = row0 + rr; gra = gra < M ? gra : M - 1;
      gll16(A + (size_t)gra * K + k0 + ch, As + (size_t)(e * 256 + wid * 64) * 8);
      gll16(BT + (size_t)(col0 + rr) * K + k0 + ch, Bs + (size_t)(e * 256 + wid * 64) * 8);
    }
    __syncthreads();
    #pragma unroll
    for (int kk = 0; kk < 2; ++kk) {
      bf16x8 af[4], bfr[4];
      #pragma unroll
      for (int m = 0; m < 4; ++m) {
        int row = wr + m * 16 + fr;
        int slot = (kk * 4 + fk4) ^ (row & 7);
        af[m] = *(const bf16x8*)(As + row * 64 + slot * 8);
      }
      #pragma unroll
      for (int n = 0; n < 4; ++n) {
        int row = wc + n * 16 + fr;
        int slot = (kk * 4 + fk4) ^ (row & 7);
        bfr[n] = *(const bf16x8*)(Bs + row * 64 + slot * 8);
      }
      #pragma unroll
      for (int m = 0; m < 4; ++m)
        #pragma unroll
        for (int n = 0; n < 4; ++n)
          acc[m][n] = __builtin_amdgcn_mfma_f32_16x16x32_bf16(af[m], bfr[n], acc[m][n], 0, 0, 0);
    }
    __syncthreads();
  }

  // ---- epilogue: stage 64-row half-tiles through LDS, emit coalesced stores ----
  const int fq = (lane >> 4) << 2;
  const int rloc = tid >> 2;            // 0..63 row within half
  const int cg = (tid & 3) << 5;        // col group 0/32/64/96
  #pragma unroll
  for (int hh = 0; hh < 2; ++hh) {
    if ((wr >> 6) == hh) {              // waves owning rows hh*64..+63
      #pragma unroll
      for (int n = 0; n < 4; ++n)
        #pragma unroll
        for (int m = 0; m < 4; ++m) {
          int col = wc + n * 16 + fr;
          *(f32x4*)&ctT[col * 68 + m * 16 + fq] = acc[m][n];
        }
    }
    __syncthreads();
    int gr = row0 + hh * 64 + rloc;
    if (gr < M) {
      int gcol0 = col0 + cg;
      #pragma unroll
      for (int k8 = 0; k8 < 4; ++k8) {  // 8 cols per chunk
        float vv[8];
        #pragma unroll
        for (int e = 0; e < 8; ++e) vv[e] = ctT[(cg + k8 * 8 + e) * 68 + rloc];
        f32x4 b0 = *(const f32x4*)&bias[gcol0 + k8 * 8];
        f32x4 b1 = *(const f32x4*)&bias[gcol0 + k8 * 8 + 4];
        #pragma unroll
        for (int e = 0; e < 8; ++e) {
          float v = vv[e] + (e < 4 ? b0[e] : b1[e - 4]);
          if (EPI == 1) {
            float u = v * (0.7978845608f + 0.0447149984f * v * v);
            float ex = __builtin_amdgcn_exp2f(u * 2.8853900818f);
            v = 0.5f * v * (2.f - 2.f * __builtin_amdgcn_rcpf(ex + 1.f));
          }
          vv[e] = v;
        }
        if (resid) {
          f32x4 r0 = *(const f32x4*)&resid[(size_t)gr * N + gcol0 + k8 * 8];
          f32x4 r1 = *(const f32x4*)&resid[(size_t)gr * N + gcol0 + k8 * 8 + 4];
          #pragma unroll
          for (int e = 0; e < 8; ++e) vv[e] += (e < 4 ? r0[e] : r1[e - 4]);
        }
        if constexpr (sizeof(OutT) == 2) {
          u16x8 pk;
          #pragma unroll
          for (int e = 0; e < 8; ++e) pk[e] = f2b(vv[e]);
          *(u16x8*)&Cout[(size_t)gr * N + gcol0 + k8 * 8] = pk;
        } else {
          f32x4 o0, o1;
          #pragma unroll
          for (int e = 0; e < 4; ++e) { o0[e] = vv[e]; o1[e] = vv[e + 4]; }
          *(f32x4*)&Cout[(size_t)gr * N + gcol0 + k8 * 8] = o0;
          *(f32x4*)&Cout[(size_t)gr * N + gcol0 + k8 * 8 + 4] = o1;
        }
      }
    }
    if (hh == 0) __syncthreads();       // protect ctT before half 2 overwrites
  }
}

// ---------- transpose + f32->bf16 ----------
__global__ __launch_bounds__(256)
void transpose_kernel(const float* __restrict__ in, unsigned short* __restrict__ out,
                      int R, int Ccols)
{
  __shared__ float t[32][33];
  int bx = blockIdx.x << 5, by = blockIdx.y << 5;
  int tx = threadIdx.x & 31, ty = threadIdx.x >> 5;
  #pragma unroll
  for (int j = ty; j < 32; j += 8)
    t[j][tx] = in[(size_t)(by + j) * Ccols + bx + tx];
  __syncthreads();
  #pragma unroll
  for (int j = ty; j < 32; j += 8)
    out[(size_t)(bx + j) * R + by + tx] = f2b(t[tx][j]);
}

// ---------- cls rows of x1 ----------
__global__ __launch_bounds__(256)
void cls_copy(const float* __restrict__ x, float* __restrict__ x1)
{
  int b = blockIdx.x;
  for (int c = threadIdx.x; c < C_; c += 256)
    x1[(size_t)b * N_ * C_ + c] = x[(size_t)b * N_ * C_ + c];
}

// ---------- CPE 3x3 dwconv, LDS-tiled ----------
__global__ __launch_bounds__(256, 2)
void cpe_tile(const float* __restrict__ x, const float* __restrict__ cw,
              const float* __restrict__ cb, float* __restrict__ x1)
{
  __shared__ __align__(16) float xt[6 * 34 * 36];
  __shared__ __align__(16) float wsm[9][32];
  __shared__ float bsm[32];
  int b = blockIdx.x, hb = blockIdx.y, cc = blockIdx.z;
  int c0 = cc * 32;
  int tid = threadIdx.x;
  for (int i = tid; i < 9 * 32; i += 256) wsm[i >> 5][i & 31] = cw[(i >> 5) * C_ + c0 + (i & 31)];
  if (tid < 32) bsm[tid] = cb[c0 + tid];
  for (int i = tid; i < 6 * 34 * 8; i += 256) {
    int g = i & 7, rw = i >> 3, w = rw % 34, r = rw / 34;
    int hh = hb * 4 - 1 + r, ww = w - 1;
    f32x4 val = (f32x4){0.f, 0.f, 0.f, 0.f};
    if (hh >= 0 && hh < 32 && ww >= 0 && ww < 32)
      val = *(const f32x4*)(x + (size_t)(b * N_ + 1 + hh * 32 + ww) * C_ + c0 + g * 4);
    *(f32x4*)&xt[(r * 34 + w) * 36 + g * 4] = val;
  }
  __syncthreads();
  int w = tid >> 3, cg = tid & 7;
  #pragma unroll
  for (int h = 0; h < 4; ++h) {
    f32x4 acc = *(const f32x4*)&bsm[cg * 4];
    #pragma unroll
    for (int kh = 0; kh < 3; ++kh)
      #pragma unroll
      for (int kw = 0; kw < 3; ++kw) {
        f32x4 v = *(const f32x4*)&xt[((h + kh) * 34 + (w + kw)) * 36 + cg * 4];
        f32x4 wv = *(const f32x4*)&wsm[kh * 3 + kw][cg * 4];
        acc += v * wv;
      }
    acc += *(const f32x4*)&xt[((h + 1) * 34 + (w + 1)) * 36 + cg * 4];
    int n = 1 + (hb * 4 + h) * 32 + w;
    *(f32x4*)&x1[(size_t)(b * N_ + n) * C_ + c0 + cg * 4] = acc;
  }
}

// ---------- LayerNorm: f32 in -> bf16 out ----------
__global__ __launch_bounds__(256)
void ln_kernel(const float* __restrict__ xin, const float* __restrict__ g,
               const float* __restrict__ bt, unsigned short* __restrict__ outp)
{
  int row = blockIdx.x;
  int tid = threadIdx.x;
  const float* xr = xin + (size_t)row * C_;
  float v0 = xr[tid], v1 = xr[tid + 256], v2 = xr[tid + 512];
  float s = v0 + v1 + v2;
  float ss = v0 * v0 + v1 * v1 + v2 * v2;
  #pragma unroll
  for (int off = 32; off >= 1; off >>= 1) {
    s += __shfl_down(s, off);
    ss += __shfl_down(ss, off);
  }
  __shared__ float sm[4], sm2[4];
  if ((tid & 63) == 0) { sm[tid >> 6] = s; sm2[tid >> 6] = ss; }
  __syncthreads();
  s = sm[0] + sm[1] + sm[2] + sm[3];
  ss = sm2[0] + sm2[1] + sm2[2] + sm2[3];
  float mean = s * (1.f / C_);
  float var = ss * (1.f / C_) - mean * mean;
  float inv = rsqrtf(var + 1e-6f);
  unsigned short* orow = outp + (size_t)row * C_;
  orow[tid]       = f2b((v0 - mean) * inv * g[tid]       + bt[tid]);
  orow[tid + 256] = f2b((v1 - mean) * inv * g[tid + 256] + bt[tid + 256]);
  orow[tid + 512] = f2b((v2 - mean) * inv * g[tid + 512] + bt[tid + 512]);
}

// ---------- k-softmax stats: two-pass (fmax pass + exp2 pass) ----------
__global__ __launch_bounds__(256)
void ksoft_part(const unsigned short* __restrict__ qkv, float* __restrict__ pmax,
                float* __restrict__ psum)
{
  int bh = blockIdx.x, part = blockIdx.y;   // (96,16)
  int b = bh / NH_, h = bh % NH_;
  int tid = threadIdx.x, c = tid & 63, sub = tid >> 6;
  float m = -1e30f;
  for (int n = part * 4 + sub; n < N_; n += 64)
    m = fmaxf(m, b2f(qkv[(size_t)(b * N_ + n) * 2304 + 768 + h * 64 + c]));
  __shared__ float ms[4][64], ss[4][64];
  ms[sub][c] = m;
  __syncthreads();
  float M = fmaxf(fmaxf(ms[0][c], ms[1][c]), fmaxf(ms[2][c], ms[3][c]));
  float s = 0.f;
  for (int n = part * 4 + sub; n < N_; n += 64)
    s += __builtin_amdgcn_exp2f((b2f(qkv[(size_t)(b * N_ + n) * 2304 + 768 + h * 64 + c]) - M) * LOG2E_);
  ss[sub][c] = s;
  __syncthreads();
  if (sub == 0) {
    pmax[((size_t)bh * 16 + part) * 64 + c] = M;
    psum[((size_t)bh * 16 + part) * 64 + c] = ss[0][c] + ss[1][c] + ss[2][c] + ss[3][c];
  }
}

__global__ __launch_bounds__(256)
void ksoft_comb(const float* __restrict__ pmax, const float* __restrict__ psum,
                float* __restrict__ colmax, float* __restrict__ colsum)
{
  int gid = blockIdx.x * 256 + threadIdx.x;   // 24 blocks
  int bh = gid >> 6, c = gid & 63;
  float M = -1e30f;
  for (int p = 0; p < 16; ++p) M = fmaxf(M, pmax[((size_t)bh * 16 + p) * 64 + c]);
  float S = 0.f;
  for (int p = 0; p < 16; ++p)
    S += psum[((size_t)bh * 16 + p) * 64 + c] *
         __builtin_amdgcn_exp2f((pmax[((size_t)bh * 16 + p) * 64 + c] - M) * LOG2E_);
  colmax[bh * 64 + c] = M;
  colsum[bh * 64 + c] = S;
}

// ---------- fa partial ----------
__global__ __launch_bounds__(256)
void fa_part(const unsigned short* __restrict__ qkv, const float* __restrict__ colmax,
             const float* __restrict__ colsum, unsigned short* __restrict__ fap)
{
  int bh = blockIdx.x, part = blockIdx.y;   // (96,16)
  int b = bh / NH_, h = bh % NH_;
  int tid = threadIdx.x;
  int n_lo = part * 65, n_hi = n_lo + 65; if (n_hi > N_) n_hi = N_;
  __shared__ float ks[8][64], vs[8][64];
  __shared__ float cm[64], cs[64];
  if (tid < 64) { cm[tid] = colmax[bh * 64 + tid]; cs[tid] = 1.f / colsum[bh * 64 + tid]; }
  __syncthreads();
  f32x4 acc4[4];
  #pragma unroll
  for (int j = 0; j < 4; ++j) acc4[j] = (f32x4){0.f, 0.f, 0.f, 0.f};
  int c = tid >> 2, dg = (tid & 3) << 4;
  for (int n0 = n_lo; n0 < n_hi; n0 += 8) {
    int nr = n_hi - n0; nr = nr < 8 ? nr : 8;
    for (int idx = tid; idx < nr * 64; idx += 256) {
      int r = idx >> 6, cc = idx & 63;
      size_t ro = (size_t)(b * N_ + n0 + r) * 2304;
      ks[r][cc] = __builtin_amdgcn_exp2f((b2f(qkv[ro + 768 + h * 64 + cc]) - cm[cc]) * LOG2E_) * cs[cc];
      vs[r][cc] = b2f(qkv[ro + 1536 + h * 64 + cc]);
    }
    __syncthreads();
    for (int r = 0; r < nr; ++r) {
      float kk = ks[r][c];
      #pragma unroll
      for (int j4 = 0; j4 < 4; ++j4)
        acc4[j4] += kk * *(const f32x4*)&vs[r][dg + j4 * 4];
    }
    __syncthreads();
  }
  #pragma unroll
  for (int j4 = 0; j4 < 4; ++j4)
    #pragma unroll
    for (int j = 0; j < 4; ++j)
      fap[((size_t)bh * 16 + part) * 4096 + c * 64 + dg + j4 * 4 + j] = f2b(acc4[j4][j]);
}

// ---------- combine fa partials, write TRANSPOSED fa_t[d][c] ----------
__global__ __launch_bounds__(256)
void fa_comb(const unsigned short* __restrict__ fap, float* __restrict__ fat)
{
  int bh = blockIdx.x;
  int tid = threadIdx.x;
  int c = tid >> 2, d0 = (tid & 3) * 16;
  #pragma unroll
  for (int j = 0; j < 16; ++j) {
    float s = 0.f;
    for (int p = 0; p < 16; ++p)
      s += b2f(fap[((size_t)bh * 16 + p) * 4096 + c * 64 + d0 + j]);
    fat[(size_t)bh * 4096 + (d0 + j) * 64 + c] = s;
  }
}

// ---------- CRPE dwconv, LDS-tiled ----------
template<int KSZ>
__global__ __launch_bounds__(256, 2)
void cv_tile(const unsigned short* __restrict__ qkv, const float* __restrict__ wgt,
             const float* __restrict__ bias, int cbase, unsigned short* __restrict__ cv)
{
  constexpr int PAD = KSZ / 2;
  constexpr int HT = 3 + KSZ;
  constexpr int WT = 31 + KSZ;
  __shared__ __align__(16) unsigned short vt[HT * WT * 72];
  __shared__ __align__(16) unsigned short wsm[KSZ * KSZ * 64];
  __shared__ float bsm[64];
  int b = blockIdx.x, hb = blockIdx.y, cc = blockIdx.z;
  int c0 = cbase + cc * 64, co0 = cc * 64;
  int tid = threadIdx.x;
  for (int i = tid; i < KSZ * KSZ * 64; i += 256)
    wsm[i] = f2b(wgt[(i >> 6) * 256 + co0 + (i & 63)]);
  if (tid < 64) bsm[tid] = bias[co0 + tid];
  for (int i = tid; i < HT * WT * 8; i += 256) {
    int g = i & 7, rw = i >> 3, w = rw % WT, r = rw / WT;
    int hh = hb * 4 - PAD + r, ww = w - PAD;
    bf16x8 val;
    #pragma unroll
    for (int z = 0; z < 8; ++z) val[z] = (__bf16)0.0f;
    if (hh >= 0 && hh < 32 && ww >= 0 && ww < 32)
      val = *(const bf16x8*)(qkv + (size_t)(b * N_ + 1 + hh * 32 + ww) * 2304 + 1536 + c0 + g * 8);
    *(bf16x8*)&vt[(r * WT + w) * 72 + g * 8] = val;
  }
  __syncthreads();
  int w = tid >> 3, cg = tid & 7;
  #pragma unroll
  for (int h = 0; h < 4; ++h) {
    float acc[8];
    #pragma unroll
    for (int j = 0; j < 8; ++j) acc[j] = bsm[cg * 8 + j];
    #pragma unroll
    for (int kh = 0; kh < KSZ; ++kh)
      #pragma unroll
      for (int kw = 0; kw < KSZ; ++kw) {
        bf16x8 v = *(const bf16x8*)&vt[((h + kh) * WT + (w + kw)) * 72 + cg * 8];
        bf16x8 wv = *(const bf16x8*)&wsm[(kh * KSZ + kw) * 64 + cg * 8];
        #pragma unroll
        for (int j = 0; j < 8; ++j)
          acc[j] += (float)v[j] * (float)wv[j];
      }
    int hw = (hb * 4 + h) * 32 + w;
    u16x8 res;
    #pragma unroll
    for (int j = 0; j < 8; ++j) res[j] = f2b(acc[j]);
    *(u16x8*)&cv[((size_t)b * 1024 + hw) * C_ + c0 + cg * 8] = res;
  }
}

// ---------- att: out = SCALE * q@fa + q*cv(shifted) ; wave-per-token ----------
__global__ __launch_bounds__(256)
void att_wave(const unsigned short* __restrict__ qkv, const float* __restrict__ fat,
              const unsigned short* __restrict__ cv, unsigned short* __restrict__ outp)
{
  int bh = blockIdx.x, chunk = blockIdx.y;   // (96,16)
  int b = bh / NH_, h = bh % NH_;
  int tid = threadIdx.x, lane = tid & 63, wid = tid >> 6;
  __shared__ __align__(16) float fas[64 * 68];
  for (int i = tid; i < 4096; i += 256)
    fas[(i >> 6) * 68 + (i & 63)] = fat[(size_t)bh * 4096 + i];
  __syncthreads();
  for (int n = chunk * 4 + wid; n < N_; n += 64) {
    const unsigned short* qrow = qkv + (size_t)(b * N_ + n) * 2304 + h * 64;
    float a = 0.f;
    #pragma unroll
    for (int c8 = 0; c8 < 8; ++c8) {
      bf16x8 qv = *(const bf16x8*)(qrow + c8 * 8);
      f32x4 f0 = *(const f32x4*)&fas[lane * 68 + c8 * 8];
      f32x4 f1 = *(const f32x4*)&fas[lane * 68 + c8 * 8 + 4];
      a += (float)qv[0] * f0[0] + (float)qv[1] * f0[1] + (float)qv[2] * f0[2] + (float)qv[3] * f0[3]
         + (float)qv[4] * f1[0] + (float)qv[5] * f1[1] + (float)qv[6] * f1[2] + (float)qv[7] * f1[3];
    }
    float val = SCALE_ * a;
    if (n >= 1) {
      float qd = b2f(qrow[lane]);
      val += qd * b2f(cv[(size_t)(b * 1024 + n - 1) * C_ + h * 64 + lane]);
    }
    outp[(size_t)(b * N_ + n) * C_ + h * 64 + lane] = f2b(val);
  }
}

// ---------- launch ----------
extern "C" void kernel_launch(void* const* d_in, const int* in_sizes, int n_in,
                              void* d_out, int out_size, void* d_ws, size_t ws_size,
                              hipStream_t stream)
{
  const float* x     = (const float*)d_in[0];
  const float* cpe_w = (const float*)d_in[3];
  const float* cpe_b = (const float*)d_in[4];
  const float* g1    = (const float*)d_in[5];
  const float* bta1  = (const float*)d_in[6];
  const float* qkv_w = (const float*)d_in[7];
  const float* qkv_b = (const float*)d_in[8];
  const float* w3    = (const float*)d_in[9];
  const float* b3    = (const float*)d_in[10];
  const float* w5    = (const float*)d_in[11];
  const float* b5    = (const float*)d_in[12];
  const float* w7    = (const float*)d_in[13];
  const float* b7    = (const float*)d_in[14];
  const float* proj_w= (const float*)d_in[15];
  const float* proj_b= (const float*)d_in[16];
  const float* g2    = (const float*)d_in[17];
  const float* bta2  = (const float*)d_in[18];
  const float* mw1   = (const float*)d_in[19];
  const float* mb1   = (const float*)d_in[20];
  const float* mw2   = (const float*)d_in[21];
  const float* mb2   = (const float*)d_in[22];

  char* ws = (char*)d_ws;
  size_t o = 0;
  auto alloc = [&](size_t bytes) { size_t r = o; o += (bytes + 255) & ~(size_t)255; return r; };
  size_t off_qkvT  = alloc(768UL * 2304 * 2);
  size_t off_projT = alloc(768UL * 768 * 2);
  size_t off_w1T   = alloc(768UL * 3072 * 2);
  size_t off_w2T   = alloc(3072UL * 768 * 2);
  size_t off_act   = alloc((size_t)M_ * C_ * 2);
  size_t off_x1    = alloc((size_t)M_ * C_ * 4);        // x1, then x2 in-place
  size_t off_qkv   = alloc((size_t)M_ * 2304 * 2);      // hid alias starts here
  size_t off_pmax  = alloc(96UL * 16 * 64 * 4);
  size_t off_psum  = alloc(96UL * 16 * 64 * 4);
  size_t off_cmax  = alloc(96UL * 64 * 4);
  size_t off_csum  = alloc(96UL * 64 * 4);
  size_t off_fat   = alloc(96UL * 4096 * 4);
  size_t off_tmp12 = alloc(96UL * 16 * 4096 * 2);       // fa partials, then cv
  size_t needed = o;

  if (ws_size < needed) {
    hipMemsetAsync(d_out, 0, (size_t)out_size * 4, stream);
    return;
  }

  unsigned short* qkvT  = (unsigned short*)(ws + off_qkvT);
  unsigned short* projT = (unsigned short*)(ws + off_projT);
  unsigned short* w1T   = (unsigned short*)(ws + off_w1T);
  unsigned short* w2T   = (unsigned short*)(ws + off_w2T);
  unsigned short* act   = (unsigned short*)(ws + off_act);
  float*          x1    = (float*)(ws + off_x1);
  unsigned short* qkvb  = (unsigned short*)(ws + off_qkv);
  float*          pmax  = (float*)(ws + off_pmax);
  float*          psum  = (float*)(ws + off_psum);
  float*          cmax  = (float*)(ws + off_cmax);
  float*          csum  = (float*)(ws + off_csum);
  float*          fat   = (float*)(ws + off_fat);
  unsigned short* tmp12 = (unsigned short*)(ws + off_tmp12);
  unsigned short* hid   = qkvb;

  dim3 blk(256);
  transpose_kernel<<<dim3(2304 / 32, 768 / 32), blk, 0, stream>>>(qkv_w, qkvT, 768, 2304);
  transpose_kernel<<<dim3(768 / 32, 768 / 32), blk, 0, stream>>>(proj_w, projT, 768, 768);
  transpose_kernel<<<dim3(3072 / 32, 768 / 32), blk, 0, stream>>>(mw1, w1T, 768, 3072);
  transpose_kernel<<<dim3(768 / 32, 3072 / 32), blk, 0, stream>>>(mw2, w2T, 3072, 768);
  cls_copy<<<8, blk, 0, stream>>>(x, x1);
  cpe_tile<<<dim3(8, 8, 24), blk, 0, stream>>>(x, cpe_w, cpe_b, x1);
  ln_kernel<<<M_, blk, 0, stream>>>(x1, g1, bta1, act);
  gemm_bt<0, unsigned short><<<65 * 18, blk, 0, stream>>>(act, qkvT, qkv_b, nullptr, qkvb, M_, 2304, 768);
  ksoft_part<<<dim3(96, 16), blk, 0, stream>>>(qkvb, pmax, psum);
  ksoft_comb<<<24, blk, 0, stream>>>(pmax, psum, cmax, csum);
  fa_part<<<dim3(96, 16), blk, 0, stream>>>(qkvb, cmax, csum, tmp12);
  fa_comb<<<96, blk, 0, stream>>>(tmp12, fat);
  cv_tile<3><<<dim3(8, 8, 4), blk, 0, stream>>>(qkvb, w3, b3, 0, tmp12);
  cv_tile<5><<<dim3(8, 8, 4), blk, 0, stream>>>(qkvb, w5, b5, 256, tmp12);
  cv_tile<7><<<dim3(8, 8, 4), blk, 0, stream>>>(qkvb, w7, b7, 512, tmp12);
  att_wave<<<dim3(96, 16), blk, 0, stream>>>(qkvb, fat, tmp12, act);
  gemm_bt<0, float><<<65 * 6, blk, 0, stream>>>(act, projT, proj_b, x1, x1, M_, 768, 768);
  ln_kernel<<<M_, blk, 0, stream>>>(x1, g2, bta2, act);
  gemm_bt<1, unsigned short><<<65 * 24, blk, 0, stream>>>(act, w1T, mb1, nullptr, hid, M_, HID_, 768);
  gemm_bt<0, float><<<65 * 6, blk, 0, stream>>>(hid, w2T, mb2, x1, (float*)d_out, M_, 768, HID_);
}